// Round 5
// baseline (568.187 us; speedup 1.0000x reference)
//
#include <hip/hip_runtime.h>

#define NN 50000
#define NE 800000
#define FIN 128
#define FH 64
#define FOUT 64
#define KC 1024
#define NB1 ((NN + 255) / 256)  // 196 chunks for the scan hierarchy

// ---------------------------------------------------------------------------
// Edge pass: in-degree histogram + pooled adjacency (stored TRANSPOSED:
// A_T[cv][cu] = A[cu][cv], so later column-ops over A become row-ops).
// ---------------------------------------------------------------------------
__global__ __launch_bounds__(256) void k_edge(const int* __restrict__ src,
                                              const int* __restrict__ dst,
                                              const int* __restrict__ cid,
                                              int* __restrict__ deg,
                                              float* __restrict__ AT) {
    int e = blockIdx.x * 256 + threadIdx.x;
    if (e >= NE) return;
    int s = src[e], d = dst[e];
    atomicAdd(&deg[d], 1);
    int cu = cid[s], cv = cid[d];
    if (cu != cv) AT[cv * KC + cu] = 1.0f;  // racing same-value stores: benign
}

// deg_p[t] = 1 + rowsum(A_T[t]); dinv_p = rsqrt.  256 thr/row for parallelism.
__global__ __launch_bounds__(256) void k_degp(const float* __restrict__ AT,
                                              float* __restrict__ dinvp) {
    __shared__ float sm[4];
    int t = blockIdx.x;
    int lane = threadIdx.x & 63, w = threadIdx.x >> 6;
    const float* row = AT + (size_t)t * KC;
    float s = 0.f;
    for (int i = threadIdx.x; i < KC; i += 256) s += row[i];
    for (int o = 32; o; o >>= 1) s += __shfl_down(s, o);
    if (lane == 0) sm[w] = s;
    __syncthreads();
    if (threadIdx.x == 0) dinvp[t] = rsqrtf(1.0f + sm[0] + sm[1] + sm[2] + sm[3]);
}

// per-node: dinv = rsqrt(deg+1); cluster counts
__global__ __launch_bounds__(256) void k_node(const int* __restrict__ deg,
                                              const int* __restrict__ cid,
                                              float* __restrict__ dinv,
                                              int* __restrict__ counts) {
    int i = blockIdx.x * 256 + threadIdx.x;
    if (i >= NN) return;
    dinv[i] = rsqrtf((float)deg[i] + 1.0f);
    atomicAdd(&counts[cid[i]], 1);
}

// --- reduce-then-scan hierarchy ---
__global__ __launch_bounds__(256) void k_scan1(const int* __restrict__ deg,
                                               int* __restrict__ partials) {
    __shared__ int ws[4];
    int i = blockIdx.x * 256 + threadIdx.x;
    int v = (i < NN) ? deg[i] : 0;
    for (int o = 32; o; o >>= 1) v += __shfl_down(v, o);
    int lane = threadIdx.x & 63, w = threadIdx.x >> 6;
    if (lane == 0) ws[w] = v;
    __syncthreads();
    if (threadIdx.x == 0)
        partials[blockIdx.x] = ws[0] + ws[1] + ws[2] + ws[3];
}

__global__ __launch_bounds__(256) void k_scan2(int* __restrict__ partials,
                                               int* __restrict__ rowptr) {
    __shared__ int sm[256];
    int t = threadIdx.x;
    int v = (t < NB1) ? partials[t] : 0;
    sm[t] = v;
    __syncthreads();
    for (int off = 1; off < 256; off <<= 1) {
        int u = (t >= off) ? sm[t - off] : 0;
        __syncthreads();
        sm[t] += u;
        __syncthreads();
    }
    if (t < NB1) partials[t] = sm[t] - v;  // exclusive
    if (t == 255) rowptr[NN] = sm[255];
}

__global__ __launch_bounds__(256) void k_scan3(int* __restrict__ deg,
                                               const int* __restrict__ partials,
                                               int* __restrict__ rowptr) {
    __shared__ int sm[256];
    int t = threadIdx.x;
    int i = blockIdx.x * 256 + t;
    int v = (i < NN) ? deg[i] : 0;
    sm[t] = v;
    __syncthreads();
    for (int off = 1; off < 256; off <<= 1) {
        int u = (t >= off) ? sm[t - off] : 0;
        __syncthreads();
        sm[t] += u;
        __syncthreads();
    }
    if (i < NN) {
        int r = partials[blockIdx.x] + sm[t] - v;
        rowptr[i] = r;
        deg[i] = r;  // fill cursor
    }
}

// Bucket-fill CSR column (source-id) list.
__global__ __launch_bounds__(256) void k_fill(const int* __restrict__ src,
                                              const int* __restrict__ dst,
                                              int* __restrict__ cursor,
                                              int* __restrict__ col) {
    int e = blockIdx.x * 256 + threadIdx.x;
    if (e >= NE) return;
    int pos = atomicAdd(&cursor[dst[e]], 1);
    col[pos] = src[e];
}

// h = x @ W1.  4 waves x 64 cols; 4 rows/thread (16-row tiles), grid-stride
// over tiles so the 32KB W-staging is amortized ~3x.  W transposed in LDS,
// stride 132 dwords: b128 reads spread uniformly over the 8 quad-banks.
// __launch_bounds__(256,4) caps VGPRs at 128 (R4's 8-row version spilled).
__global__ __launch_bounds__(256, 4) void k_gemm1(const float* __restrict__ x,
                                                  const float* __restrict__ W1,
                                                  float* __restrict__ h) {
    __shared__ float Wt[FH][FIN + 4];  // 33792 B
    int t = threadIdx.x;
    for (int i = t; i < FIN * FH; i += 256) Wt[i & 63][i >> 6] = W1[i];
    __syncthreads();
    int col = t & 63, grp = t >> 6;
    const int L = FIN / 4;  // 32
    const float4* x4 = (const float4*)x;
    const int NT = NN / 16;  // 3125 tiles, NN % 16 == 0
    for (int tile = blockIdx.x; tile < NT; tile += gridDim.x) {
        int row0 = tile * 16 + grp * 4;
        const float4* p0 = x4 + (size_t)row0 * L;
        const float4* p1 = p0 + L;
        const float4* p2 = p1 + L;
        const float4* p3 = p2 + L;
        float acc0 = 0.f, acc1 = 0.f, acc2 = 0.f, acc3 = 0.f;
        for (int k4 = 0; k4 < L; ++k4) {
            float4 w = *(const float4*)&Wt[col][k4 * 4];
            float4 a0 = p0[k4], a1 = p1[k4], a2 = p2[k4], a3 = p3[k4];
            acc0 = fmaf(a0.x, w.x, fmaf(a0.y, w.y, fmaf(a0.z, w.z, fmaf(a0.w, w.w, acc0))));
            acc1 = fmaf(a1.x, w.x, fmaf(a1.y, w.y, fmaf(a1.z, w.z, fmaf(a1.w, w.w, acc1))));
            acc2 = fmaf(a2.x, w.x, fmaf(a2.y, w.y, fmaf(a2.z, w.z, fmaf(a2.w, w.w, acc2))));
            acc3 = fmaf(a3.x, w.x, fmaf(a3.y, w.y, fmaf(a3.z, w.z, fmaf(a3.w, w.w, acc3))));
        }
        float* hp = h + (size_t)row0 * FH + col;
        hp[0] = acc0;
        hp[FH] = acc1;
        hp[2 * FH] = acc2;
        hp[3 * FH] = acc3;
    }
}

// Gather aggregation + fused x1 epilogue + cluster-sum atomics.
__global__ __launch_bounds__(256) void k_gather(const int* __restrict__ rowptr,
                                                const int* __restrict__ col,
                                                const float* __restrict__ dinv,
                                                const float* __restrict__ h,
                                                const float* __restrict__ b1,
                                                const int* __restrict__ cid,
                                                float* __restrict__ x1,
                                                float* __restrict__ sums) {
    int lane = threadIdx.x & 63;
    int node = blockIdx.x * 4 + (threadIdx.x >> 6);
    if (node >= NN) return;
    int rp = rowptr[node], re = rowptr[node + 1];
    float acc = 0.f;
    for (int base = rp; base < re; base += 64) {
        int cnt = min(64, re - base);
        int s = (lane < cnt) ? col[base + lane] : 0;
        float w = (lane < cnt) ? dinv[s] : 0.f;
        for (int j = 0; j < cnt; ++j) {
            int ss = __shfl(s, j);
            float ww = __shfl(w, j);
            acc = fmaf(ww, h[(size_t)ss * FH + lane], acc);
        }
    }
    float di = dinv[node];
    float v = di * acc + di * di * h[(size_t)node * FH + lane] + b1[lane];
    v = fmaxf(v, 0.f);
    x1[(size_t)node * FH + lane] = v;
    unsafeAtomicAdd(&sums[(size_t)cid[node] * FH + lane], v);
}

// x_p = sums/counts; g[s] = dinv_p[s] * (x_p[s] @ W2)
__global__ __launch_bounds__(64) void k_pool(const float* __restrict__ sums,
                                             const int* __restrict__ counts,
                                             const float* __restrict__ W2,
                                             const float* __restrict__ dinvp,
                                             float* __restrict__ g) {
    __shared__ float xp[FH];
    int s = blockIdx.x, f = threadIdx.x;
    float cnt = fmaxf((float)counts[s], 1.0f);
    xp[f] = sums[(size_t)s * FH + f] / cnt;
    __syncthreads();
    float acc = 0.f;
    for (int j = 0; j < FH; ++j) acc = fmaf(xp[j], W2[j * FH + f], acc);
    g[(size_t)s * FH + f] = dinvp[s] * acc;
}

// xp2[t] = dinvp[t]*(g[t] + sum_s AT[t,s]*g[s]) + b2.
// One block (4 waves) per target row; each wave covers 256 sources; LDS reduce.
__global__ __launch_bounds__(256) void k_xp2(const float* __restrict__ AT,
                                             const float* __restrict__ g,
                                             const float* __restrict__ dinvp,
                                             const float* __restrict__ b2,
                                             float* __restrict__ xp2) {
    __shared__ float sm[4][FH];
    int t = blockIdx.x;
    int lane = threadIdx.x & 63, w = threadIdx.x >> 6;
    const float* row = AT + (size_t)t * KC;
    float acc = 0.f;
    int sb0 = w * 256;
    for (int sb = sb0; sb < sb0 + 256; sb += 64) {
        float a = row[sb + lane];
        for (int j = 0; j < 64; ++j) {
            float aj = __shfl(a, j);
            acc = fmaf(aj, g[(size_t)(sb + j) * FH + lane], acc);
        }
    }
    sm[w][lane] = acc;
    __syncthreads();
    if (w == 0) {
        acc = sm[0][lane] + sm[1][lane] + sm[2][lane] + sm[3][lane]
            + g[(size_t)t * FH + lane];  // self-loop
        xp2[(size_t)t * FH + lane] = dinvp[t] * acc + b2[lane];
    }
}

// out = xp2[cid] + relu(alpha) * (x1 @ W_skip + b_skip).  Same 4-row scheme.
__global__ __launch_bounds__(256, 4) void k_final(const float* __restrict__ x1,
                                                  const float* __restrict__ Wsk,
                                                  const float* __restrict__ bsk,
                                                  const float* __restrict__ xp2,
                                                  const int* __restrict__ cid,
                                                  const float* __restrict__ alpha,
                                                  float* __restrict__ out) {
    __shared__ float Wt[FOUT][FH + 4];  // 17408 B
    int t = threadIdx.x;
    for (int i = t; i < FH * FOUT; i += 256) Wt[i & 63][i >> 6] = Wsk[i];
    __syncthreads();
    float al = fmaxf(alpha[0], 0.f);
    int col = t & 63, grp = t >> 6;
    const int L = FH / 4;  // 16
    const float4* x4 = (const float4*)x1;
    const int NT = NN / 16;
    for (int tile = blockIdx.x; tile < NT; tile += gridDim.x) {
        int row0 = tile * 16 + grp * 4;
        const float4* p0 = x4 + (size_t)row0 * L;
        const float4* p1 = p0 + L;
        const float4* p2 = p1 + L;
        const float4* p3 = p2 + L;
        float acc0 = 0.f, acc1 = 0.f, acc2 = 0.f, acc3 = 0.f;
        for (int k4 = 0; k4 < L; ++k4) {
            float4 w = *(const float4*)&Wt[col][k4 * 4];
            float4 a0 = p0[k4], a1 = p1[k4], a2 = p2[k4], a3 = p3[k4];
            acc0 = fmaf(a0.x, w.x, fmaf(a0.y, w.y, fmaf(a0.z, w.z, fmaf(a0.w, w.w, acc0))));
            acc1 = fmaf(a1.x, w.x, fmaf(a1.y, w.y, fmaf(a1.z, w.z, fmaf(a1.w, w.w, acc1))));
            acc2 = fmaf(a2.x, w.x, fmaf(a2.y, w.y, fmaf(a2.z, w.z, fmaf(a2.w, w.w, acc2))));
            acc3 = fmaf(a3.x, w.x, fmaf(a3.y, w.y, fmaf(a3.z, w.z, fmaf(a3.w, w.w, acc3))));
        }
        float bb = bsk[col];
        int c0 = cid[row0 + 0], c1 = cid[row0 + 1], c2 = cid[row0 + 2], c3 = cid[row0 + 3];
        float* op = out + (size_t)row0 * FOUT + col;
        op[0]        = xp2[(size_t)c0 * FOUT + col] + al * (acc0 + bb);
        op[FOUT]     = xp2[(size_t)c1 * FOUT + col] + al * (acc1 + bb);
        op[2 * FOUT] = xp2[(size_t)c2 * FOUT + col] + al * (acc2 + bb);
        op[3 * FOUT] = xp2[(size_t)c3 * FOUT + col] + al * (acc3 + bb);
    }
}

extern "C" void kernel_launch(void* const* d_in, const int* in_sizes, int n_in,
                              void* d_out, int out_size, void* d_ws, size_t ws_size,
                              hipStream_t stream) {
    const float* x    = (const float*)d_in[0];
    const int*   ei   = (const int*)d_in[1];
    const int*   cid  = (const int*)d_in[2];
    const float* W1   = (const float*)d_in[3];
    const float* b1   = (const float*)d_in[4];
    const float* W2   = (const float*)d_in[5];
    const float* b2   = (const float*)d_in[6];
    const float* Wsk  = (const float*)d_in[7];
    const float* bsk  = (const float*)d_in[8];
    const float* alpha= (const float*)d_in[9];
    float* out = (float*)d_out;
    const int* src = ei;
    const int* dst = ei + NE;

    // workspace layout: zero-init region first (one memset covers it)
    char* ws = (char*)d_ws;
    size_t cur = 0;
    auto alloc = [&](size_t nb) { cur = (cur + 255) & ~(size_t)255; size_t o = cur; cur += nb; return o; };
    size_t o_sums = alloc((size_t)KC * FH * 4);
    size_t o_AT   = alloc((size_t)KC * KC * 4);
    size_t o_deg  = alloc((size_t)NN * 4);      // becomes CSR cursor after scan
    size_t o_cnt  = alloc((size_t)KC * 4);
    size_t zero_bytes = cur;
    size_t o_x1   = alloc((size_t)NN * FH * 4);
    size_t o_h    = alloc((size_t)NN * FH * 4);
    size_t o_rp   = alloc((size_t)(NN + 1) * 4);
    size_t o_col  = alloc((size_t)NE * 4);
    size_t o_dinv = alloc((size_t)NN * 4);
    size_t o_g    = alloc((size_t)KC * FH * 4);
    size_t o_xp2  = alloc((size_t)KC * FH * 4);
    size_t o_dinvp= alloc((size_t)KC * 4);
    size_t o_part = alloc((size_t)NB1 * 4);
    (void)ws_size; (void)in_sizes; (void)n_in; (void)out_size;

    float* sums = (float*)(ws + o_sums);
    float* AT   = (float*)(ws + o_AT);
    int*   deg  = (int*)(ws + o_deg);
    int*   cnt  = (int*)(ws + o_cnt);
    float* x1   = (float*)(ws + o_x1);
    float* h    = (float*)(ws + o_h);
    int*   rp   = (int*)(ws + o_rp);
    int*   colb = (int*)(ws + o_col);
    float* dinv = (float*)(ws + o_dinv);
    float* g    = (float*)(ws + o_g);
    float* xp2  = (float*)(ws + o_xp2);
    float* dinvp= (float*)(ws + o_dinvp);
    int*   part = (int*)(ws + o_part);

    hipMemsetAsync(d_ws, 0, zero_bytes, stream);

    k_edge  <<<(NE + 255) / 256, 256, 0, stream>>>(src, dst, cid, deg, AT);
    k_degp  <<<KC, 256, 0, stream>>>(AT, dinvp);
    k_node  <<<(NN + 255) / 256, 256, 0, stream>>>(deg, cid, dinv, cnt);
    k_scan1 <<<NB1, 256, 0, stream>>>(deg, part);
    k_scan2 <<<1, 256, 0, stream>>>(part, rp);
    k_scan3 <<<NB1, 256, 0, stream>>>(deg, part, rp);
    k_fill  <<<(NE + 255) / 256, 256, 0, stream>>>(src, dst, deg, colb);
    k_gemm1 <<<1024, 256, 0, stream>>>(x, W1, h);
    k_gather<<<(NN + 3) / 4, 256, 0, stream>>>(rp, colb, dinv, h, b1, cid, x1, sums);
    k_pool  <<<KC, 64, 0, stream>>>(sums, cnt, W2, dinvp, g);
    k_xp2   <<<KC, 256, 0, stream>>>(AT, g, dinvp, b2, xp2);
    k_final <<<1024, 256, 0, stream>>>(x1, Wsk, bsk, xp2, cid, alpha, out);
}

// Round 6
// 357.077 us; speedup vs baseline: 1.5912x; 1.5912x over previous
//
#include <hip/hip_runtime.h>

#define NN 50000
#define NE 800000
#define FIN 128
#define FH 64
#define FOUT 64
#define KC 1024
#define NB1 ((NN + 255) / 256)  // 196 chunks for the scan hierarchy

// ---------------------------------------------------------------------------
// Edge pass: in-degree histogram + pooled adjacency (stored TRANSPOSED:
// A_T[cv][cu] = A[cu][cv], so later column-ops over A become row-ops).
// ---------------------------------------------------------------------------
__global__ __launch_bounds__(256) void k_edge(const int* __restrict__ src,
                                              const int* __restrict__ dst,
                                              const int* __restrict__ cid,
                                              int* __restrict__ deg,
                                              float* __restrict__ AT) {
    int e = blockIdx.x * 256 + threadIdx.x;
    if (e >= NE) return;
    int s = src[e], d = dst[e];
    atomicAdd(&deg[d], 1);
    int cu = cid[s], cv = cid[d];
    if (cu != cv) AT[cv * KC + cu] = 1.0f;  // racing same-value stores: benign
}

// deg_p[t] = 1 + rowsum(A_T[t]); dinv_p = rsqrt.  256 thr/row.
__global__ __launch_bounds__(256) void k_degp(const float* __restrict__ AT,
                                              float* __restrict__ dinvp) {
    __shared__ float sm[4];
    int t = blockIdx.x;
    int lane = threadIdx.x & 63, w = threadIdx.x >> 6;
    const float* row = AT + (size_t)t * KC;
    float s = 0.f;
    for (int i = threadIdx.x; i < KC; i += 256) s += row[i];
    for (int o = 32; o; o >>= 1) s += __shfl_down(s, o);
    if (lane == 0) sm[w] = s;
    __syncthreads();
    if (threadIdx.x == 0) dinvp[t] = rsqrtf(1.0f + sm[0] + sm[1] + sm[2] + sm[3]);
}

// per-node: dinv = rsqrt(deg+1); cluster counts
__global__ __launch_bounds__(256) void k_node(const int* __restrict__ deg,
                                              const int* __restrict__ cid,
                                              float* __restrict__ dinv,
                                              int* __restrict__ counts) {
    int i = blockIdx.x * 256 + threadIdx.x;
    if (i >= NN) return;
    dinv[i] = rsqrtf((float)deg[i] + 1.0f);
    atomicAdd(&counts[cid[i]], 1);
}

// --- reduce-then-scan hierarchy ---
__global__ __launch_bounds__(256) void k_scan1(const int* __restrict__ deg,
                                               int* __restrict__ partials) {
    __shared__ int ws[4];
    int i = blockIdx.x * 256 + threadIdx.x;
    int v = (i < NN) ? deg[i] : 0;
    for (int o = 32; o; o >>= 1) v += __shfl_down(v, o);
    int lane = threadIdx.x & 63, w = threadIdx.x >> 6;
    if (lane == 0) ws[w] = v;
    __syncthreads();
    if (threadIdx.x == 0)
        partials[blockIdx.x] = ws[0] + ws[1] + ws[2] + ws[3];
}

__global__ __launch_bounds__(256) void k_scan2(int* __restrict__ partials,
                                               int* __restrict__ rowptr) {
    __shared__ int sm[256];
    int t = threadIdx.x;
    int v = (t < NB1) ? partials[t] : 0;
    sm[t] = v;
    __syncthreads();
    for (int off = 1; off < 256; off <<= 1) {
        int u = (t >= off) ? sm[t - off] : 0;
        __syncthreads();
        sm[t] += u;
        __syncthreads();
    }
    if (t < NB1) partials[t] = sm[t] - v;  // exclusive
    if (t == 255) rowptr[NN] = sm[255];
}

__global__ __launch_bounds__(256) void k_scan3(int* __restrict__ deg,
                                               const int* __restrict__ partials,
                                               int* __restrict__ rowptr) {
    __shared__ int sm[256];
    int t = threadIdx.x;
    int i = blockIdx.x * 256 + t;
    int v = (i < NN) ? deg[i] : 0;
    sm[t] = v;
    __syncthreads();
    for (int off = 1; off < 256; off <<= 1) {
        int u = (t >= off) ? sm[t - off] : 0;
        __syncthreads();
        sm[t] += u;
        __syncthreads();
    }
    if (i < NN) {
        int r = partials[blockIdx.x] + sm[t] - v;
        rowptr[i] = r;
        deg[i] = r;  // fill cursor
    }
}

// Bucket-fill CSR column (source-id) list.
__global__ __launch_bounds__(256) void k_fill(const int* __restrict__ src,
                                              const int* __restrict__ dst,
                                              int* __restrict__ cursor,
                                              int* __restrict__ col) {
    int e = blockIdx.x * 256 + threadIdx.x;
    if (e >= NE) return;
    int pos = atomicAdd(&cursor[dst[e]], 1);
    col[pos] = src[e];
}

// h = x @ W1.  R3 structure (44 VGPR, no spill, scalar W-reads are 2-way
// bank-free) but COLUMN-SPLIT: each block does 32 of 64 cols -> LDS 16 KB
// -> ~8 blocks/CU (vs R3's 4) for 2x latency hiding.  4 rows/thread.
// blockIdx.x: bit0 = col half, rest = 32-row tile.
__global__ __launch_bounds__(256) void k_gemm1(const float* __restrict__ x,
                                               const float* __restrict__ W1,
                                               float* __restrict__ h) {
    __shared__ float Ws[FIN * 32];  // 16 KB, [k][c], c = half's 32 cols
    int t = threadIdx.x;
    int half = blockIdx.x & 1;
    int rblk = blockIdx.x >> 1;
    for (int i = t; i < FIN * 32; i += 256) {
        int k = i >> 5, c = i & 31;
        Ws[i] = W1[k * FH + half * 32 + c];
    }
    __syncthreads();
    int col = t & 31, grp = t >> 5;  // 8 row-groups x 4 rows = 32 rows/block
    int row0 = rblk * 32 + grp * 4;
    const int L = FIN / 4;  // 32
    const float4* x4 = (const float4*)x;
    int r0 = min(row0 + 0, NN - 1), r1 = min(row0 + 1, NN - 1);
    int r2 = min(row0 + 2, NN - 1), r3 = min(row0 + 3, NN - 1);
    const float4* p0 = x4 + (size_t)r0 * L;
    const float4* p1 = x4 + (size_t)r1 * L;
    const float4* p2 = x4 + (size_t)r2 * L;
    const float4* p3 = x4 + (size_t)r3 * L;
    float acc0 = 0.f, acc1 = 0.f, acc2 = 0.f, acc3 = 0.f;
    for (int k4 = 0; k4 < L; ++k4) {
        float4 a0 = p0[k4], a1 = p1[k4], a2 = p2[k4], a3 = p3[k4];
        const float* wp = &Ws[(k4 * 4) * 32 + col];
        float w0 = wp[0], w1 = wp[32], w2 = wp[64], w3 = wp[96];
        acc0 = fmaf(a0.x, w0, fmaf(a0.y, w1, fmaf(a0.z, w2, fmaf(a0.w, w3, acc0))));
        acc1 = fmaf(a1.x, w0, fmaf(a1.y, w1, fmaf(a1.z, w2, fmaf(a1.w, w3, acc1))));
        acc2 = fmaf(a2.x, w0, fmaf(a2.y, w1, fmaf(a2.z, w2, fmaf(a2.w, w3, acc2))));
        acc3 = fmaf(a3.x, w0, fmaf(a3.y, w1, fmaf(a3.z, w2, fmaf(a3.w, w3, acc3))));
    }
    int oc = half * 32 + col;
    if (row0 + 0 < NN) h[(size_t)(row0 + 0) * FH + oc] = acc0;
    if (row0 + 1 < NN) h[(size_t)(row0 + 1) * FH + oc] = acc1;
    if (row0 + 2 < NN) h[(size_t)(row0 + 2) * FH + oc] = acc2;
    if (row0 + 3 < NN) h[(size_t)(row0 + 3) * FH + oc] = acc3;
}

// Gather aggregation + fused x1 epilogue + cluster-sum atomics.
__global__ __launch_bounds__(256) void k_gather(const int* __restrict__ rowptr,
                                                const int* __restrict__ col,
                                                const float* __restrict__ dinv,
                                                const float* __restrict__ h,
                                                const float* __restrict__ b1,
                                                const int* __restrict__ cid,
                                                float* __restrict__ x1,
                                                float* __restrict__ sums) {
    int lane = threadIdx.x & 63;
    int node = blockIdx.x * 4 + (threadIdx.x >> 6);
    if (node >= NN) return;
    int rp = rowptr[node], re = rowptr[node + 1];
    float acc = 0.f;
    for (int base = rp; base < re; base += 64) {
        int cnt = min(64, re - base);
        int s = (lane < cnt) ? col[base + lane] : 0;
        float w = (lane < cnt) ? dinv[s] : 0.f;
        for (int j = 0; j < cnt; ++j) {
            int ss = __shfl(s, j);
            float ww = __shfl(w, j);
            acc = fmaf(ww, h[(size_t)ss * FH + lane], acc);
        }
    }
    float di = dinv[node];
    float v = di * acc + di * di * h[(size_t)node * FH + lane] + b1[lane];
    v = fmaxf(v, 0.f);
    x1[(size_t)node * FH + lane] = v;
    unsafeAtomicAdd(&sums[(size_t)cid[node] * FH + lane], v);
}

// x_p = sums/counts; g[s] = dinv_p[s] * (x_p[s] @ W2)
__global__ __launch_bounds__(64) void k_pool(const float* __restrict__ sums,
                                             const int* __restrict__ counts,
                                             const float* __restrict__ W2,
                                             const float* __restrict__ dinvp,
                                             float* __restrict__ g) {
    __shared__ float xp[FH];
    int s = blockIdx.x, f = threadIdx.x;
    float cnt = fmaxf((float)counts[s], 1.0f);
    xp[f] = sums[(size_t)s * FH + f] / cnt;
    __syncthreads();
    float acc = 0.f;
    for (int j = 0; j < FH; ++j) acc = fmaf(xp[j], W2[j * FH + f], acc);
    g[(size_t)s * FH + f] = dinvp[s] * acc;
}

// xp2[t] = dinvp[t]*(g[t] + sum_s AT[t,s]*g[s]) + b2.
// One block (4 waves) per target row; each wave covers 256 sources; LDS reduce.
__global__ __launch_bounds__(256) void k_xp2(const float* __restrict__ AT,
                                             const float* __restrict__ g,
                                             const float* __restrict__ dinvp,
                                             const float* __restrict__ b2,
                                             float* __restrict__ xp2) {
    __shared__ float sm[4][FH];
    int t = blockIdx.x;
    int lane = threadIdx.x & 63, w = threadIdx.x >> 6;
    const float* row = AT + (size_t)t * KC;
    float acc = 0.f;
    int sb0 = w * 256;
    for (int sb = sb0; sb < sb0 + 256; sb += 64) {
        float a = row[sb + lane];
        for (int j = 0; j < 64; ++j) {
            float aj = __shfl(a, j);
            acc = fmaf(aj, g[(size_t)(sb + j) * FH + lane], acc);
        }
    }
    sm[w][lane] = acc;
    __syncthreads();
    if (w == 0) {
        acc = sm[0][lane] + sm[1][lane] + sm[2][lane] + sm[3][lane]
            + g[(size_t)t * FH + lane];  // self-loop
        xp2[(size_t)t * FH + lane] = dinvp[t] * acc + b2[lane];
    }
}

// out = xp2[cid] + relu(alpha) * (x1 @ W_skip + b_skip).  Column-split like
// k_gemm1: 32 cols/block, LDS 8 KB.
__global__ __launch_bounds__(256) void k_final(const float* __restrict__ x1,
                                               const float* __restrict__ Wsk,
                                               const float* __restrict__ bsk,
                                               const float* __restrict__ xp2,
                                               const int* __restrict__ cid,
                                               const float* __restrict__ alpha,
                                               float* __restrict__ out) {
    __shared__ float Ws[FH * 32];  // 8 KB
    int t = threadIdx.x;
    int half = blockIdx.x & 1;
    int rblk = blockIdx.x >> 1;
    for (int i = t; i < FH * 32; i += 256) {
        int k = i >> 5, c = i & 31;
        Ws[i] = Wsk[k * FOUT + half * 32 + c];
    }
    __syncthreads();
    float al = fmaxf(alpha[0], 0.f);
    int col = t & 31, grp = t >> 5;
    int row0 = rblk * 32 + grp * 4;
    const int L = FH / 4;  // 16
    const float4* x4 = (const float4*)x1;
    int r0 = min(row0 + 0, NN - 1), r1 = min(row0 + 1, NN - 1);
    int r2 = min(row0 + 2, NN - 1), r3 = min(row0 + 3, NN - 1);
    const float4* p0 = x4 + (size_t)r0 * L;
    const float4* p1 = x4 + (size_t)r1 * L;
    const float4* p2 = x4 + (size_t)r2 * L;
    const float4* p3 = x4 + (size_t)r3 * L;
    float acc0 = 0.f, acc1 = 0.f, acc2 = 0.f, acc3 = 0.f;
    for (int k4 = 0; k4 < L; ++k4) {
        float4 a0 = p0[k4], a1 = p1[k4], a2 = p2[k4], a3 = p3[k4];
        const float* wp = &Ws[(k4 * 4) * 32 + col];
        float w0 = wp[0], w1 = wp[32], w2 = wp[64], w3 = wp[96];
        acc0 = fmaf(a0.x, w0, fmaf(a0.y, w1, fmaf(a0.z, w2, fmaf(a0.w, w3, acc0))));
        acc1 = fmaf(a1.x, w0, fmaf(a1.y, w1, fmaf(a1.z, w2, fmaf(a1.w, w3, acc1))));
        acc2 = fmaf(a2.x, w0, fmaf(a2.y, w1, fmaf(a2.z, w2, fmaf(a2.w, w3, acc2))));
        acc3 = fmaf(a3.x, w0, fmaf(a3.y, w1, fmaf(a3.z, w2, fmaf(a3.w, w3, acc3))));
    }
    int oc = half * 32 + col;
    float bb = bsk[oc];
    if (row0 + 0 < NN) out[(size_t)(row0 + 0) * FOUT + oc] = xp2[(size_t)cid[r0] * FOUT + oc] + al * (acc0 + bb);
    if (row0 + 1 < NN) out[(size_t)(row0 + 1) * FOUT + oc] = xp2[(size_t)cid[r1] * FOUT + oc] + al * (acc1 + bb);
    if (row0 + 2 < NN) out[(size_t)(row0 + 2) * FOUT + oc] = xp2[(size_t)cid[r2] * FOUT + oc] + al * (acc2 + bb);
    if (row0 + 3 < NN) out[(size_t)(row0 + 3) * FOUT + oc] = xp2[(size_t)cid[r3] * FOUT + oc] + al * (acc3 + bb);
}

extern "C" void kernel_launch(void* const* d_in, const int* in_sizes, int n_in,
                              void* d_out, int out_size, void* d_ws, size_t ws_size,
                              hipStream_t stream) {
    const float* x    = (const float*)d_in[0];
    const int*   ei   = (const int*)d_in[1];
    const int*   cid  = (const int*)d_in[2];
    const float* W1   = (const float*)d_in[3];
    const float* b1   = (const float*)d_in[4];
    const float* W2   = (const float*)d_in[5];
    const float* b2   = (const float*)d_in[6];
    const float* Wsk  = (const float*)d_in[7];
    const float* bsk  = (const float*)d_in[8];
    const float* alpha= (const float*)d_in[9];
    float* out = (float*)d_out;
    const int* src = ei;
    const int* dst = ei + NE;

    // workspace layout: zero-init region first (one memset covers it)
    char* ws = (char*)d_ws;
    size_t cur = 0;
    auto alloc = [&](size_t nb) { cur = (cur + 255) & ~(size_t)255; size_t o = cur; cur += nb; return o; };
    size_t o_sums = alloc((size_t)KC * FH * 4);
    size_t o_AT   = alloc((size_t)KC * KC * 4);
    size_t o_deg  = alloc((size_t)NN * 4);      // becomes CSR cursor after scan
    size_t o_cnt  = alloc((size_t)KC * 4);
    size_t zero_bytes = cur;
    size_t o_x1   = alloc((size_t)NN * FH * 4);
    size_t o_h    = alloc((size_t)NN * FH * 4);
    size_t o_rp   = alloc((size_t)(NN + 1) * 4);
    size_t o_col  = alloc((size_t)NE * 4);
    size_t o_dinv = alloc((size_t)NN * 4);
    size_t o_g    = alloc((size_t)KC * FH * 4);
    size_t o_xp2  = alloc((size_t)KC * FH * 4);
    size_t o_dinvp= alloc((size_t)KC * 4);
    size_t o_part = alloc((size_t)NB1 * 4);
    (void)ws_size; (void)in_sizes; (void)n_in; (void)out_size;

    float* sums = (float*)(ws + o_sums);
    float* AT   = (float*)(ws + o_AT);
    int*   deg  = (int*)(ws + o_deg);
    int*   cnt  = (int*)(ws + o_cnt);
    float* x1   = (float*)(ws + o_x1);
    float* h    = (float*)(ws + o_h);
    int*   rp   = (int*)(ws + o_rp);
    int*   colb = (int*)(ws + o_col);
    float* dinv = (float*)(ws + o_dinv);
    float* g    = (float*)(ws + o_g);
    float* xp2  = (float*)(ws + o_xp2);
    float* dinvp= (float*)(ws + o_dinvp);
    int*   part = (int*)(ws + o_part);

    hipMemsetAsync(d_ws, 0, zero_bytes, stream);

    const int NRB = (NN + 31) / 32;  // 1563 row-blocks of 32
    k_edge  <<<(NE + 255) / 256, 256, 0, stream>>>(src, dst, cid, deg, AT);
    k_degp  <<<KC, 256, 0, stream>>>(AT, dinvp);
    k_node  <<<(NN + 255) / 256, 256, 0, stream>>>(deg, cid, dinv, cnt);
    k_scan1 <<<NB1, 256, 0, stream>>>(deg, part);
    k_scan2 <<<1, 256, 0, stream>>>(part, rp);
    k_scan3 <<<NB1, 256, 0, stream>>>(deg, part, rp);
    k_fill  <<<(NE + 255) / 256, 256, 0, stream>>>(src, dst, deg, colb);
    k_gemm1 <<<NRB * 2, 256, 0, stream>>>(x, W1, h);
    k_gather<<<(NN + 3) / 4, 256, 0, stream>>>(rp, colb, dinv, h, b1, cid, x1, sums);
    k_pool  <<<KC, 64, 0, stream>>>(sums, cnt, W2, dinvp, g);
    k_xp2   <<<KC, 256, 0, stream>>>(AT, g, dinvp, b2, xp2);
    k_final <<<NRB * 2, 256, 0, stream>>>(x1, Wsk, bsk, xp2, cid, alpha, out);
}

// Round 7
// 319.538 us; speedup vs baseline: 1.7781x; 1.1175x over previous
//
#include <hip/hip_runtime.h>

#define NN 50000
#define NE 800000
#define FIN 128
#define FH 64
#define FOUT 64
#define KC 1024
#define NB1 ((NN + 255) / 256)  // 196 chunks for the scan hierarchy

// ---------------------------------------------------------------------------
// Edge pass: in-degree histogram + pooled adjacency (stored TRANSPOSED).
// ---------------------------------------------------------------------------
__global__ __launch_bounds__(256) void k_edge(const int* __restrict__ src,
                                              const int* __restrict__ dst,
                                              const int* __restrict__ cid,
                                              int* __restrict__ deg,
                                              float* __restrict__ AT) {
    int e = blockIdx.x * 256 + threadIdx.x;
    if (e >= NE) return;
    int s = src[e], d = dst[e];
    atomicAdd(&deg[d], 1);
    int cu = cid[s], cv = cid[d];
    if (cu != cv) AT[cv * KC + cu] = 1.0f;  // racing same-value stores: benign
}

// deg_p[t] = 1 + rowsum(A_T[t]); dinv_p = rsqrt.  256 thr/row.
__global__ __launch_bounds__(256) void k_degp(const float* __restrict__ AT,
                                              float* __restrict__ dinvp) {
    __shared__ float sm[4];
    int t = blockIdx.x;
    int lane = threadIdx.x & 63, w = threadIdx.x >> 6;
    const float* row = AT + (size_t)t * KC;
    float s = 0.f;
    for (int i = threadIdx.x; i < KC; i += 256) s += row[i];
    for (int o = 32; o; o >>= 1) s += __shfl_down(s, o);
    if (lane == 0) sm[w] = s;
    __syncthreads();
    if (threadIdx.x == 0) dinvp[t] = rsqrtf(1.0f + sm[0] + sm[1] + sm[2] + sm[3]);
}

// per-node: dinv = rsqrt(deg+1); cluster counts
__global__ __launch_bounds__(256) void k_node(const int* __restrict__ deg,
                                              const int* __restrict__ cid,
                                              float* __restrict__ dinv,
                                              int* __restrict__ counts) {
    int i = blockIdx.x * 256 + threadIdx.x;
    if (i >= NN) return;
    dinv[i] = rsqrtf((float)deg[i] + 1.0f);
    atomicAdd(&counts[cid[i]], 1);
}

// --- reduce-then-scan hierarchy ---
__global__ __launch_bounds__(256) void k_scan1(const int* __restrict__ deg,
                                               int* __restrict__ partials) {
    __shared__ int ws[4];
    int i = blockIdx.x * 256 + threadIdx.x;
    int v = (i < NN) ? deg[i] : 0;
    for (int o = 32; o; o >>= 1) v += __shfl_down(v, o);
    int lane = threadIdx.x & 63, w = threadIdx.x >> 6;
    if (lane == 0) ws[w] = v;
    __syncthreads();
    if (threadIdx.x == 0)
        partials[blockIdx.x] = ws[0] + ws[1] + ws[2] + ws[3];
}

__global__ __launch_bounds__(256) void k_scan2(int* __restrict__ partials,
                                               int* __restrict__ rowptr) {
    __shared__ int sm[256];
    int t = threadIdx.x;
    int v = (t < NB1) ? partials[t] : 0;
    sm[t] = v;
    __syncthreads();
    for (int off = 1; off < 256; off <<= 1) {
        int u = (t >= off) ? sm[t - off] : 0;
        __syncthreads();
        sm[t] += u;
        __syncthreads();
    }
    if (t < NB1) partials[t] = sm[t] - v;  // exclusive
    if (t == 255) rowptr[NN] = sm[255];
}

__global__ __launch_bounds__(256) void k_scan3(int* __restrict__ deg,
                                               const int* __restrict__ partials,
                                               int* __restrict__ rowptr) {
    __shared__ int sm[256];
    int t = threadIdx.x;
    int i = blockIdx.x * 256 + t;
    int v = (i < NN) ? deg[i] : 0;
    sm[t] = v;
    __syncthreads();
    for (int off = 1; off < 256; off <<= 1) {
        int u = (t >= off) ? sm[t - off] : 0;
        __syncthreads();
        sm[t] += u;
        __syncthreads();
    }
    if (i < NN) {
        int r = partials[blockIdx.x] + sm[t] - v;
        rowptr[i] = r;
        deg[i] = r;  // fill cursor
    }
}

// Bucket-fill CSR column (source-id) list.
__global__ __launch_bounds__(256) void k_fill(const int* __restrict__ src,
                                              const int* __restrict__ dst,
                                              int* __restrict__ cursor,
                                              int* __restrict__ col) {
    int e = blockIdx.x * 256 + threadIdx.x;
    if (e >= NE) return;
    int pos = atomicAdd(&cursor[dst[e]], 1);
    col[pos] = src[e];
}

// h = x @ W1.  Column-split (32 cols/block) like R6, but the 32-row x-tile is
// STAGED THROUGH LDS with coalesced float4 loads (R6's per-thread broadcast
// global loads moved only 16B/VMEM-inst -> VMEM-latency bound, VALUBusy 23%).
// Inner loop: LDS broadcast reads (free) + scalar W reads (2-way, free).
__global__ __launch_bounds__(256) void k_gemm1(const float* __restrict__ x,
                                               const float* __restrict__ W1,
                                               float* __restrict__ h) {
    __shared__ float Ws[FIN * 32];   // 16 KB, [k][c]
    __shared__ float Xs[32 * FIN];   // 16 KB, [r][k]
    int t = threadIdx.x;
    int half = blockIdx.x & 1;
    int rblk = blockIdx.x >> 1;
    int row_base = rblk * 32;
    for (int i = t; i < FIN * 32; i += 256) {
        int k = i >> 5, c = i & 31;
        Ws[i] = W1[k * FH + half * 32 + c];
    }
    {
        const float4* x4 = (const float4*)x;
        float4* xs4 = (float4*)Xs;
        // 32 rows x 32 float4 = 1024 float4; 4 passes of 256 coalesced lanes
        for (int i = t; i < 32 * 32; i += 256) {
            int r = i >> 5, k4 = i & 31;
            int row = row_base + r;
            float4 v = make_float4(0.f, 0.f, 0.f, 0.f);
            if (row < NN) v = x4[(size_t)row * 32 + k4];
            xs4[i] = v;
        }
    }
    __syncthreads();
    int col = t & 31, grp = t >> 5;  // 8 row-groups x 4 rows
    int r0 = grp * 4;
    const float4* p0 = (const float4*)&Xs[(r0 + 0) * FIN];
    const float4* p1 = (const float4*)&Xs[(r0 + 1) * FIN];
    const float4* p2 = (const float4*)&Xs[(r0 + 2) * FIN];
    const float4* p3 = (const float4*)&Xs[(r0 + 3) * FIN];
    float acc0 = 0.f, acc1 = 0.f, acc2 = 0.f, acc3 = 0.f;
    for (int k4 = 0; k4 < FIN / 4; ++k4) {
        float4 a0 = p0[k4], a1 = p1[k4], a2 = p2[k4], a3 = p3[k4];
        const float* wp = &Ws[(k4 * 4) * 32 + col];
        float w0 = wp[0], w1 = wp[32], w2 = wp[64], w3 = wp[96];
        acc0 = fmaf(a0.x, w0, fmaf(a0.y, w1, fmaf(a0.z, w2, fmaf(a0.w, w3, acc0))));
        acc1 = fmaf(a1.x, w0, fmaf(a1.y, w1, fmaf(a1.z, w2, fmaf(a1.w, w3, acc1))));
        acc2 = fmaf(a2.x, w0, fmaf(a2.y, w1, fmaf(a2.z, w2, fmaf(a2.w, w3, acc2))));
        acc3 = fmaf(a3.x, w0, fmaf(a3.y, w1, fmaf(a3.z, w2, fmaf(a3.w, w3, acc3))));
    }
    int row0 = row_base + r0;
    int oc = half * 32 + col;
    if (row0 + 0 < NN) h[(size_t)(row0 + 0) * FH + oc] = acc0;
    if (row0 + 1 < NN) h[(size_t)(row0 + 1) * FH + oc] = acc1;
    if (row0 + 2 < NN) h[(size_t)(row0 + 2) * FH + oc] = acc2;
    if (row0 + 3 < NN) h[(size_t)(row0 + 3) * FH + oc] = acc3;
}

// Gather aggregation + fused x1 epilogue + cluster-sum atomics.
__global__ __launch_bounds__(256) void k_gather(const int* __restrict__ rowptr,
                                                const int* __restrict__ col,
                                                const float* __restrict__ dinv,
                                                const float* __restrict__ h,
                                                const float* __restrict__ b1,
                                                const int* __restrict__ cid,
                                                float* __restrict__ x1,
                                                float* __restrict__ sums) {
    int lane = threadIdx.x & 63;
    int node = blockIdx.x * 4 + (threadIdx.x >> 6);
    if (node >= NN) return;
    int rp = rowptr[node], re = rowptr[node + 1];
    float acc = 0.f;
    for (int base = rp; base < re; base += 64) {
        int cnt = min(64, re - base);
        int s = (lane < cnt) ? col[base + lane] : 0;
        float w = (lane < cnt) ? dinv[s] : 0.f;
        for (int j = 0; j < cnt; ++j) {
            int ss = __shfl(s, j);
            float ww = __shfl(w, j);
            acc = fmaf(ww, h[(size_t)ss * FH + lane], acc);
        }
    }
    float di = dinv[node];
    float v = di * acc + di * di * h[(size_t)node * FH + lane] + b1[lane];
    v = fmaxf(v, 0.f);
    x1[(size_t)node * FH + lane] = v;
    unsafeAtomicAdd(&sums[(size_t)cid[node] * FH + lane], v);
}

// x_p = sums/counts; g[s] = dinv_p[s] * (x_p[s] @ W2)
__global__ __launch_bounds__(64) void k_pool(const float* __restrict__ sums,
                                             const int* __restrict__ counts,
                                             const float* __restrict__ W2,
                                             const float* __restrict__ dinvp,
                                             float* __restrict__ g) {
    __shared__ float xp[FH];
    int s = blockIdx.x, f = threadIdx.x;
    float cnt = fmaxf((float)counts[s], 1.0f);
    xp[f] = sums[(size_t)s * FH + f] / cnt;
    __syncthreads();
    float acc = 0.f;
    for (int j = 0; j < FH; ++j) acc = fmaf(xp[j], W2[j * FH + f], acc);
    g[(size_t)s * FH + f] = dinvp[s] * acc;
}

// xp2[t] = dinvp[t]*(g[t] + sum_s AT[t,s]*g[s]) + b2.
__global__ __launch_bounds__(256) void k_xp2(const float* __restrict__ AT,
                                             const float* __restrict__ g,
                                             const float* __restrict__ dinvp,
                                             const float* __restrict__ b2,
                                             float* __restrict__ xp2) {
    __shared__ float sm[4][FH];
    int t = blockIdx.x;
    int lane = threadIdx.x & 63, w = threadIdx.x >> 6;
    const float* row = AT + (size_t)t * KC;
    float acc = 0.f;
    int sb0 = w * 256;
    for (int sb = sb0; sb < sb0 + 256; sb += 64) {
        float a = row[sb + lane];
        for (int j = 0; j < 64; ++j) {
            float aj = __shfl(a, j);
            acc = fmaf(aj, g[(size_t)(sb + j) * FH + lane], acc);
        }
    }
    sm[w][lane] = acc;
    __syncthreads();
    if (w == 0) {
        acc = sm[0][lane] + sm[1][lane] + sm[2][lane] + sm[3][lane]
            + g[(size_t)t * FH + lane];  // self-loop
        xp2[(size_t)t * FH + lane] = dinvp[t] * acc + b2[lane];
    }
}

// out = xp2[cid] + relu(alpha) * (x1 @ W_skip + b_skip).  Column-split +
// LDS-staged x1 tile (same fix as k_gemm1).
__global__ __launch_bounds__(256) void k_final(const float* __restrict__ x1,
                                               const float* __restrict__ Wsk,
                                               const float* __restrict__ bsk,
                                               const float* __restrict__ xp2,
                                               const int* __restrict__ cid,
                                               const float* __restrict__ alpha,
                                               float* __restrict__ out) {
    __shared__ float Ws[FH * 32];   // 8 KB, [k][c]
    __shared__ float Xs[32 * FH];   // 8 KB, [r][k]
    int t = threadIdx.x;
    int half = blockIdx.x & 1;
    int rblk = blockIdx.x >> 1;
    int row_base = rblk * 32;
    for (int i = t; i < FH * 32; i += 256) {
        int k = i >> 5, c = i & 31;
        Ws[i] = Wsk[k * FOUT + half * 32 + c];
    }
    {
        const float4* x4 = (const float4*)x1;
        float4* xs4 = (float4*)Xs;
        // 32 rows x 16 float4 = 512 float4; 2 passes
        for (int i = t; i < 32 * 16; i += 256) {
            int r = i >> 4, k4 = i & 15;
            int row = row_base + r;
            float4 v = make_float4(0.f, 0.f, 0.f, 0.f);
            if (row < NN) v = x4[(size_t)row * 16 + k4];
            xs4[i] = v;
        }
    }
    __syncthreads();
    float al = fmaxf(alpha[0], 0.f);
    int col = t & 31, grp = t >> 5;
    int r0 = grp * 4;
    const float4* p0 = (const float4*)&Xs[(r0 + 0) * FH];
    const float4* p1 = (const float4*)&Xs[(r0 + 1) * FH];
    const float4* p2 = (const float4*)&Xs[(r0 + 2) * FH];
    const float4* p3 = (const float4*)&Xs[(r0 + 3) * FH];
    float acc0 = 0.f, acc1 = 0.f, acc2 = 0.f, acc3 = 0.f;
    for (int k4 = 0; k4 < FH / 4; ++k4) {
        float4 a0 = p0[k4], a1 = p1[k4], a2 = p2[k4], a3 = p3[k4];
        const float* wp = &Ws[(k4 * 4) * 32 + col];
        float w0 = wp[0], w1 = wp[32], w2 = wp[64], w3 = wp[96];
        acc0 = fmaf(a0.x, w0, fmaf(a0.y, w1, fmaf(a0.z, w2, fmaf(a0.w, w3, acc0))));
        acc1 = fmaf(a1.x, w0, fmaf(a1.y, w1, fmaf(a1.z, w2, fmaf(a1.w, w3, acc1))));
        acc2 = fmaf(a2.x, w0, fmaf(a2.y, w1, fmaf(a2.z, w2, fmaf(a2.w, w3, acc2))));
        acc3 = fmaf(a3.x, w0, fmaf(a3.y, w1, fmaf(a3.z, w2, fmaf(a3.w, w3, acc3))));
    }
    int row0 = row_base + r0;
    int oc = half * 32 + col;
    float bb = bsk[oc];
    if (row0 + 0 < NN) out[(size_t)(row0 + 0) * FOUT + oc] = xp2[(size_t)cid[row0 + 0] * FOUT + oc] + al * (acc0 + bb);
    if (row0 + 1 < NN) out[(size_t)(row0 + 1) * FOUT + oc] = xp2[(size_t)cid[row0 + 1] * FOUT + oc] + al * (acc1 + bb);
    if (row0 + 2 < NN) out[(size_t)(row0 + 2) * FOUT + oc] = xp2[(size_t)cid[row0 + 2] * FOUT + oc] + al * (acc2 + bb);
    if (row0 + 3 < NN) out[(size_t)(row0 + 3) * FOUT + oc] = xp2[(size_t)cid[row0 + 3] * FOUT + oc] + al * (acc3 + bb);
}

extern "C" void kernel_launch(void* const* d_in, const int* in_sizes, int n_in,
                              void* d_out, int out_size, void* d_ws, size_t ws_size,
                              hipStream_t stream) {
    const float* x    = (const float*)d_in[0];
    const int*   ei   = (const int*)d_in[1];
    const int*   cid  = (const int*)d_in[2];
    const float* W1   = (const float*)d_in[3];
    const float* b1   = (const float*)d_in[4];
    const float* W2   = (const float*)d_in[5];
    const float* b2   = (const float*)d_in[6];
    const float* Wsk  = (const float*)d_in[7];
    const float* bsk  = (const float*)d_in[8];
    const float* alpha= (const float*)d_in[9];
    float* out = (float*)d_out;
    const int* src = ei;
    const int* dst = ei + NE;

    // workspace layout: zero-init region first (one memset covers it)
    char* ws = (char*)d_ws;
    size_t cur = 0;
    auto alloc = [&](size_t nb) { cur = (cur + 255) & ~(size_t)255; size_t o = cur; cur += nb; return o; };
    size_t o_sums = alloc((size_t)KC * FH * 4);
    size_t o_AT   = alloc((size_t)KC * KC * 4);
    size_t o_deg  = alloc((size_t)NN * 4);      // becomes CSR cursor after scan
    size_t o_cnt  = alloc((size_t)KC * 4);
    size_t zero_bytes = cur;
    size_t o_x1   = alloc((size_t)NN * FH * 4);
    size_t o_h    = alloc((size_t)NN * FH * 4);
    size_t o_rp   = alloc((size_t)(NN + 1) * 4);
    size_t o_col  = alloc((size_t)NE * 4);
    size_t o_dinv = alloc((size_t)NN * 4);
    size_t o_g    = alloc((size_t)KC * FH * 4);
    size_t o_xp2  = alloc((size_t)KC * FH * 4);
    size_t o_dinvp= alloc((size_t)KC * 4);
    size_t o_part = alloc((size_t)NB1 * 4);
    (void)ws_size; (void)in_sizes; (void)n_in; (void)out_size;

    float* sums = (float*)(ws + o_sums);
    float* AT   = (float*)(ws + o_AT);
    int*   deg  = (int*)(ws + o_deg);
    int*   cnt  = (int*)(ws + o_cnt);
    float* x1   = (float*)(ws + o_x1);
    float* h    = (float*)(ws + o_h);
    int*   rp   = (int*)(ws + o_rp);
    int*   colb = (int*)(ws + o_col);
    float* dinv = (float*)(ws + o_dinv);
    float* g    = (float*)(ws + o_g);
    float* xp2  = (float*)(ws + o_xp2);
    float* dinvp= (float*)(ws + o_dinvp);
    int*   part = (int*)(ws + o_part);

    hipMemsetAsync(d_ws, 0, zero_bytes, stream);

    const int NRB = (NN + 31) / 32;  // 1563 row-blocks of 32
    k_edge  <<<(NE + 255) / 256, 256, 0, stream>>>(src, dst, cid, deg, AT);
    k_degp  <<<KC, 256, 0, stream>>>(AT, dinvp);
    k_node  <<<(NN + 255) / 256, 256, 0, stream>>>(deg, cid, dinv, cnt);
    k_scan1 <<<NB1, 256, 0, stream>>>(deg, part);
    k_scan2 <<<1, 256, 0, stream>>>(part, rp);
    k_scan3 <<<NB1, 256, 0, stream>>>(deg, part, rp);
    k_fill  <<<(NE + 255) / 256, 256, 0, stream>>>(src, dst, deg, colb);
    k_gemm1 <<<NRB * 2, 256, 0, stream>>>(x, W1, h);
    k_gather<<<(NN + 3) / 4, 256, 0, stream>>>(rp, colb, dinv, h, b1, cid, x1, sums);
    k_pool  <<<KC, 64, 0, stream>>>(sums, cnt, W2, dinvp, g);
    k_xp2   <<<KC, 256, 0, stream>>>(AT, g, dinvp, b2, xp2);
    k_final <<<NRB * 2, 256, 0, stream>>>(x1, Wsk, bsk, xp2, cid, alpha, out);
}